// Round 4
// baseline (406.633 us; speedup 1.0000x reference)
//
#include <hip/hip_runtime.h>
#include <hip/hip_bf16.h>

typedef unsigned short u16;
typedef unsigned int   u32;

__device__ __forceinline__ float b2f(u16 u) { return __uint_as_float(((u32)u) << 16); }
__device__ __forceinline__ float sigmoidf(float x) { return 1.0f / (1.0f + __expf(-x)); }
__device__ __forceinline__ float rdl(float v, int lane) {
    return __uint_as_float(__builtin_amdgcn_readlane(__float_as_uint(v), lane));
}
// read element i of tensor p with runtime dtype: bf16 (isf=0) or fp32 (isf=1)
__device__ __forceinline__ float ldany(const void* p, int i, int isf) {
    return isf ? ((const float*)p)[i] : b2f(((const u16*)p)[i]);
}

// ws float layout: [0..67]=folded P  [68]=flag_x [69]=flag_adj
// [80..127]=Whh [128..139]=bhh [144..1007]=cW [1008..1019]=cB [1020..1027]=oW [1028..1029]=oB
// [2048..) halo (32 KB of floats)
#define HALO_OFF 2048

// ---------------- K0: probe dtypes (x, adj only — large-sample), canonicalize, fold ----------------
__global__ __launch_bounds__(256) void k0_setup(
    const void* x, const void* adj, const void* gat_W, const void* att_src,
    const void* att_dst, const void* gat_bias, const void* Wih, const void* Whh,
    const void* bih, const void* bhh, const void* cW, const void* cB,
    const void* oW, const void* oB, float* __restrict__ W) {
    __shared__ float gw[256], asv[64], adv[64], gbv[64], wihs[768];
    __shared__ int badx, bada;
    int tid = threadIdx.x;
    if (tid == 0) { badx = 0; bada = 0; }
    __syncthreads();
    // probe: read first 256 u16s as bf16; fp32-backed data has random low-halves -> |v|>=64 w.h.p.
    {
        float vx = b2f(((const u16*)x)[tid]);
        float va = b2f(((const u16*)adj)[tid]);
        if (!(fabsf(vx) < 64.0f)) badx = 1;
        if (!(fabsf(va) < 64.0f)) bada = 1;
    }
    __syncthreads();
    int fx = badx, fa = bada;
    int fw = fx;   // harness converts dtypes all-or-none; use the high-confidence flag for weights

    for (int i = tid; i < 256; i += 256) gw[i] = ldany(gat_W, i, fw);
    if (tid < 64) {
        asv[tid] = ldany(att_src, tid, fw);
        adv[tid] = ldany(att_dst, tid, fw);
        gbv[tid] = ldany(gat_bias, tid, fw);
    }
    for (int i = tid; i < 768; i += 256) wihs[i] = ldany(Wih, i, fw);
    __syncthreads();

    if (tid < 68) {
        int t = tid;
        float s = 0.0f;
        if (t < 4)       { for (int h = 0; h < 64; ++h) s += gw[t * 64 + h] * asv[h]; }
        else if (t < 8)  { int f = t - 4;  for (int h = 0; h < 64; ++h) s += gw[f * 64 + h] * adv[h]; }
        else if (t < 56) { int f = (t - 8) / 12, g = (t - 8) % 12;
                           for (int h = 0; h < 64; ++h) s += gw[f * 64 + h] * wihs[g * 64 + h]; }
        else             { int g = t - 56;
                           for (int h = 0; h < 64; ++h) s += gbv[h] * wihs[g * 64 + h];
                           s += ldany(bih, g, fw); }
        W[t] = s;
    }
    if (tid < 48) W[80 + tid]  = ldany(Whh, tid, fw);
    if (tid < 12) W[128 + tid] = ldany(bhh, tid, fw);
    for (int i = tid; i < 864; i += 256) W[144 + i] = ldany(cW, i, fw);
    if (tid < 12) W[1008 + tid] = ldany(cB, tid, fw);
    if (tid < 8)  W[1020 + tid] = ldany(oW, tid, fw);
    if (tid < 2)  W[1028 + tid] = ldany(oB, tid, fw);
    if (tid == 0) { W[68] = (float)fx; W[69] = (float)fa; }
}

// ---------------- K1: fused GAT -> GRU -> Conv -> Linear per (b, t2) ----------------
__global__ __launch_bounds__(512) void k_main(
    const void* __restrict__ x, const void* __restrict__ adj,
    const float* __restrict__ W, float* __restrict__ halo, float2* __restrict__ out) {
    __shared__ float As[512][4];
    __shared__ float gblk[8][64][4];
    __shared__ float CC[4][12], c0v[12], Whh[12][4], bhhv[12];
    __shared__ float cw[12][8][3][3], cbv[12], owv[2][4], obv[2];

    int tid = threadIdx.x;
    int bt = blockIdx.x;               // b*8 + t2
    int b = bt >> 3, t2 = bt & 7;

    if (tid < 48) { CC[tid / 12][tid % 12] = W[8 + tid]; Whh[tid >> 2][tid & 3] = W[80 + tid]; }
    else if (tid >= 64 && tid < 76)  { int g = tid - 64; c0v[g] = W[56 + g]; bhhv[g] = W[128 + g]; }
    else if (tid >= 96 && tid < 108) cbv[tid - 96] = W[1008 + (tid - 96)];
    else if (tid >= 128 && tid < 136){ int k = tid - 128; owv[k >> 2][k & 3] = W[1020 + k]; }
    else if (tid >= 160 && tid < 162) obv[tid - 160] = W[1028 + (tid - 160)];
    for (int idx = tid; idx < 864; idx += 512) {
        int co = idx / 72, r = idx % 72;
        cw[co][r / 9][(r % 9) / 3][r % 3] = W[144 + idx];
    }

    float vs0 = W[0], vs1 = W[1], vs2 = W[2], vs3 = W[3];
    float vd0 = W[4], vd1 = W[5], vd2 = W[6], vd3 = W[7];
    int fx = (int)W[68], fa = (int)W[69];

    // own x row (row = tid within slice bt)
    float xi0, xi1, xi2, xi3;
    if (fx) {
        float4 v = ((const float4*)x)[(size_t)bt * 512 + tid];
        xi0 = v.x; xi1 = v.y; xi2 = v.z; xi3 = v.w;
    } else {
        uint2 v = ((const uint2*)x)[(size_t)bt * 512 + tid];
        xi0 = b2f(v.x & 0xffff); xi1 = b2f(v.x >> 16);
        xi2 = b2f(v.y & 0xffff); xi3 = b2f(v.y >> 16);
    }
    float adsti = xi0 * vd0 + xi1 * vd1 + xi2 * vd2 + xi3 * vd3;

    int i = tid, lane = tid & 63;
    float a0 = 0, a1 = 0, a2 = 0, a3 = 0, wsum = 0;
    size_t abase = (size_t)bt * 262144 + i;
    for (int jt = 0; jt < 8; ++jt) {
        float tx0, tx1, tx2, tx3;
        if (fx) {
            float4 v = ((const float4*)x)[(size_t)bt * 512 + jt * 64 + lane];
            tx0 = v.x; tx1 = v.y; tx2 = v.z; tx3 = v.w;
        } else {
            uint2 v = ((const uint2*)x)[(size_t)bt * 512 + jt * 64 + lane];
            tx0 = b2f(v.x & 0xffff); tx1 = b2f(v.x >> 16);
            tx2 = b2f(v.y & 0xffff); tx3 = b2f(v.y >> 16);
        }
        float ta = tx0 * vs0 + tx1 * vs1 + tx2 * vs2 + tx3 * vs3;   // a_src[j]
        if (fa) {
            const float* apj = (const float*)adj + abase + (size_t)(jt * 64) * 512;
            #pragma unroll 16
            for (int jj = 0; jj < 64; ++jj) {
                float av = apj[(size_t)jj * 512];      // adj[b,t,j,i], coalesced in i
                float xj0 = rdl(tx0, jj), xj1 = rdl(tx1, jj);
                float xj2 = rdl(tx2, jj), xj3 = rdl(tx3, jj);
                float aj = rdl(ta, jj);
                float s = adsti + aj;
                float e = fmaxf(s, 0.2f * s);          // leaky_relu(0.2)
                float w = __expf(e);                   // softmax shift-invariant; args O(1)
                int j = jt * 64 + jj;
                w = (av != 0.0f || j == i) ? w : 0.0f;
                a0 = fmaf(w, xj0, a0); a1 = fmaf(w, xj1, a1);
                a2 = fmaf(w, xj2, a2); a3 = fmaf(w, xj3, a3);
                wsum += w;
            }
        } else {
            const u16* apj = (const u16*)adj + abase + (size_t)(jt * 64) * 512;
            #pragma unroll 16
            for (int jj = 0; jj < 64; ++jj) {
                u16 av = apj[(size_t)jj * 512];
                float xj0 = rdl(tx0, jj), xj1 = rdl(tx1, jj);
                float xj2 = rdl(tx2, jj), xj3 = rdl(tx3, jj);
                float aj = rdl(ta, jj);
                float s = adsti + aj;
                float e = fmaxf(s, 0.2f * s);
                float w = __expf(e);
                int j = jt * 64 + jj;
                w = (av != 0 || j == i) ? w : 0.0f;
                a0 = fmaf(w, xj0, a0); a1 = fmaf(w, xj1, a1);
                a2 = fmaf(w, xj2, a2); a3 = fmaf(w, xj3, a3);
                wsum += w;
            }
        }
    }
    { float inv = 1.0f / wsum;
      As[i][0] = a0 * inv; As[i][1] = a1 * inv; As[i][2] = a2 * inv; As[i][3] = a3 * inv; }
    __syncthreads();

    // GRU: sequence q = t2*64 + l reads As[l*8+t] (faithful raw .view)
    if (tid < 64) {
        int l = tid;
        float h0 = 0, h1 = 0, h2 = 0, h3 = 0;
        #pragma unroll
        for (int t = 0; t < 8; ++t) {
            const float* av = As[l * 8 + t];
            float A0 = av[0], A1 = av[1], A2 = av[2], A3 = av[3];
            float gx[12], gh[12];
            #pragma unroll
            for (int g = 0; g < 12; ++g) {
                gx[g] = c0v[g] + A0 * CC[0][g] + A1 * CC[1][g] + A2 * CC[2][g] + A3 * CC[3][g];
                gh[g] = bhhv[g] + h0 * Whh[g][0] + h1 * Whh[g][1] + h2 * Whh[g][2] + h3 * Whh[g][3];
            }
            float hp[4] = {h0, h1, h2, h3}, hn[4];
            #pragma unroll
            for (int k = 0; k < 4; ++k) {
                float r = sigmoidf(gx[k] + gh[k]);
                float z = sigmoidf(gx[4 + k] + gh[4 + k]);
                float nc = tanhf(gx[8 + k] + r * gh[8 + k]);
                hn[k] = (1.0f - z) * nc + z * hp[k];
            }
            h0 = hn[0]; h1 = hn[1]; h2 = hn[2]; h3 = hn[3];
            gblk[t][l][0] = h0; gblk[t][l][1] = h1; gblk[t][l][2] = h2; gblk[t][l][3] = h3;
        }
    }
    __syncthreads();

    // export 4 edge rows (m in {0,1,62,63}) for the boundary kernel
    if (tid < 128) {
        int s = tid >> 5, ch = (tid >> 2) & 7, f = tid & 3;
        int mrow = (s == 0) ? 0 : (s == 1) ? 1 : (s == 2) ? 62 : 63;
        halo[((size_t)bt * 4 + s) * 32 + ch * 4 + f] = gblk[ch][mrow][f];
    }

    // conv3x3(8->12) + linear(4->2) for interior rows m in [1,62]; fp32 float2 output
    for (int task = tid; task < 744; task += 512) {
        int m = 1 + task / 12, co = task % 12;
        float y0 = cbv[co], y1 = y0, y2 = y0, y3 = y0;
        #pragma unroll
        for (int ci = 0; ci < 8; ++ci) {
            #pragma unroll
            for (int kh = 0; kh < 3; ++kh) {
                const float* rr = gblk[ci][m + kh - 1];
                float w0 = cw[co][ci][kh][0], w1 = cw[co][ci][kh][1], w2 = cw[co][ci][kh][2];
                y0 += rr[0] * w1 + rr[1] * w2;
                y1 += rr[0] * w0 + rr[1] * w1 + rr[2] * w2;
                y2 += rr[1] * w0 + rr[2] * w1 + rr[3] * w2;
                y3 += rr[2] * w0 + rr[3] * w1;
            }
        }
        float o0 = obv[0] + y0 * owv[0][0] + y1 * owv[0][1] + y2 * owv[0][2] + y3 * owv[0][3];
        float o1 = obv[1] + y0 * owv[1][0] + y1 * owv[1][1] + y2 * owv[1][2] + y3 * owv[1][3];
        if (!(o0 == o0 && fabsf(o0) < 1e30f)) o0 = 10000.0f;   // diagnostic sentinel
        if (!(o1 == o1 && fabsf(o1) < 1e30f)) o1 = 10000.0f;
        out[(size_t)(b * 12 + co) * 512 + (t2 * 64 + m)] = make_float2(o0, o1);
    }
}

// ---------------- K2: boundary rows (n mod 64 in {0,63}) ----------------
__global__ __launch_bounds__(256) void k_halo(
    const float* __restrict__ W, const float* __restrict__ halo, float2* __restrict__ out) {
    __shared__ float cw[12][8][3][3], cbv[12], owv[2][4], obv[2];
    int tid = threadIdx.x, b = blockIdx.x;
    for (int idx = tid; idx < 864; idx += 256) {
        int co = idx / 72, r = idx % 72;
        cw[co][r / 9][(r % 9) / 3][r % 3] = W[144 + idx];
    }
    if (tid < 12) cbv[tid] = W[1008 + tid];
    if (tid >= 32 && tid < 40) { int k = tid - 32; owv[k >> 2][k & 3] = W[1020 + k]; }
    if (tid >= 64 && tid < 66) obv[tid - 64] = W[1028 + (tid - 64)];
    __syncthreads();
    if (tid < 192) {
        int t2 = tid / 24, r = tid % 24, edge = r / 12, co = r % 12;
        int n = t2 * 64 + (edge ? 63 : 0);
        float y0 = cbv[co], y1 = y0, y2 = y0, y3 = y0;
        for (int kh = 0; kh < 3; ++kh) {
            int rn = n + kh - 1;
            bool ok = (rn >= 0 && rn <= 511);
            int tb = min(max(rn >> 6, 0), 7);
            int mm = rn & 63;
            int slot = (mm == 0) ? 0 : (mm == 1) ? 1 : (mm == 62) ? 2 : 3;
            const float* hb = halo + ((size_t)((b * 8 + tb) * 4 + slot)) * 32;
            for (int ci = 0; ci < 8; ++ci) {
                float r0 = ok ? hb[ci * 4 + 0] : 0.0f;
                float r1 = ok ? hb[ci * 4 + 1] : 0.0f;
                float r2 = ok ? hb[ci * 4 + 2] : 0.0f;
                float r3 = ok ? hb[ci * 4 + 3] : 0.0f;
                float w0 = cw[co][ci][kh][0], w1 = cw[co][ci][kh][1], w2 = cw[co][ci][kh][2];
                y0 += r0 * w1 + r1 * w2;
                y1 += r0 * w0 + r1 * w1 + r2 * w2;
                y2 += r1 * w0 + r2 * w1 + r3 * w2;
                y3 += r2 * w0 + r3 * w1;
            }
        }
        float o0 = obv[0] + y0 * owv[0][0] + y1 * owv[0][1] + y2 * owv[0][2] + y3 * owv[0][3];
        float o1 = obv[1] + y0 * owv[1][0] + y1 * owv[1][1] + y2 * owv[1][2] + y3 * owv[1][3];
        if (!(o0 == o0 && fabsf(o0) < 1e30f)) o0 = 10000.0f;
        if (!(o1 == o1 && fabsf(o1) < 1e30f)) o1 = 10000.0f;
        out[(size_t)(b * 12 + co) * 512 + n] = make_float2(o0, o1);
    }
}

extern "C" void kernel_launch(void* const* d_in, const int* in_sizes, int n_in,
                              void* d_out, int out_size, void* d_ws, size_t ws_size,
                              hipStream_t stream) {
    float* W    = (float*)d_ws;
    float* halo = W + HALO_OFF;   // 128 KB region; total ws use ~139 KB

    k0_setup<<<1, 256, 0, stream>>>(d_in[0], d_in[1], d_in[2], d_in[3], d_in[4],
                                    d_in[5], d_in[6], d_in[7], d_in[8], d_in[9],
                                    d_in[10], d_in[11], d_in[12], d_in[13], W);
    k_main<<<256, 512, 0, stream>>>(d_in[0], d_in[1], W, halo, (float2*)d_out);
    k_halo<<<32, 256, 0, stream>>>(W, halo, (float2*)d_out);
}